// Round 9
// baseline (186.342 us; speedup 1.0000x reference)
//
#include <hip/hip_runtime.h>
#include <hip/hip_fp16.h>

#define N_NODES 100000
#define N_EDGES 1600000
// single-level partition: 128-node buckets, bucket = dst >> 7
#define NCB 782             // ceil(N/128)
#define CAPC 2560           // mean 2046, sigma ~45 -> +11 sigma, 64B-aligned
#define P1_BLOCKS 391       // ceil((E/4)/1024) int4-threads
#define BKN 128             // nodes per CSR bucket
#define NBF_G 1563          // gather grid: 64 nodes/block, covers N + sentinel
#define NFIN_B 3128         // k_gfin grid: 8 XCD classes x 391

// cursor1[] is COUNTS (0-initialized via hipMemsetAsync); absolute position =
// bucket*CAPC + relative offset.
// rowPack[n] = rowBeg | (deg << 21): beg < 782*2560 = 2.0M < 2^21; deg capped
// at 2047. dinv recomputed as rsqrtf(deg+1) by consumers.
// Layer-2 activations are stored as TWO half-tables p2a (ch 0-15, mu input)
// and p2b (ch 16-31, logvar input), 3.2 MB each -- each fits one XCD's 4 MB
// private L2, enabling the XCD-affine split gather in k_gfin.

// ---------------- pass 1: partition edges into 782 buckets ----------------
__global__ __launch_bounds__(1024) void k_part1(const int* __restrict__ src,
                                                const int* __restrict__ dst,
                                                int* __restrict__ cursor1,
                                                unsigned* __restrict__ packed1) {
    __shared__ int bh[NCB];
    __shared__ int base[NCB];
    int t = threadIdx.x;
    for (int i = t; i < NCB; i += 1024) bh[i] = 0;
    __syncthreads();
    int g = blockIdx.x * 1024 + t;       // int4-group index; 4 edges/thread
    int d[4], s[4], r[4];
    if (g < N_EDGES / 4) {
        int4 d4 = reinterpret_cast<const int4*>(dst)[g];
        int4 s4 = reinterpret_cast<const int4*>(src)[g];
        d[0] = d4.x; d[1] = d4.y; d[2] = d4.z; d[3] = d4.w;
        s[0] = s4.x; s[1] = s4.y; s[2] = s4.z; s[3] = s4.w;
    } else {
        d[0] = d[1] = d[2] = d[3] = -1;
    }
#pragma unroll
    for (int j = 0; j < 4; ++j)
        if (d[j] >= 0) r[j] = atomicAdd(&bh[((unsigned)d[j]) >> 7], 1);
    __syncthreads();
    for (int i = t; i < NCB; i += 1024) {
        int c = bh[i];
        base[i] = i * CAPC + ((c > 0) ? atomicAdd(&cursor1[i], c) : 0);
    }
    __syncthreads();
#pragma unroll
    for (int j = 0; j < 4; ++j) {
        if (d[j] < 0) continue;
        unsigned dd = (unsigned)d[j];
        int b = dd >> 7;
        int pos = base[b] + r[j];
        if (pos < (b + 1) * CAPC)   // statistically impossible overflow guard
            packed1[pos] = ((dd & 127u) << 17) | (unsigned)s[j];
    }
}

// ---------------- fused: per-bucket CSR build + rowPack + p1 = dinv*(x@W1) ----
__global__ __launch_bounds__(512) void k_csrx(const unsigned* __restrict__ packed1,
                                              const int* __restrict__ cursor1,
                                              const float* __restrict__ x,
                                              const float* __restrict__ W1,
                                              unsigned* __restrict__ rowPack,
                                              int* __restrict__ srcSorted,
                                              __half* __restrict__ p1) {
    __shared__ int cnt[BKN];
    __shared__ int scn[BKN];
    __shared__ int stt[BKN];
    __shared__ float sW[1024];
    int t = threadIdx.x;
    int b = blockIdx.x;
    int seg0 = b * CAPC;
    int cc = cursor1[b]; if (cc > CAPC) cc = CAPC;
    int segEnd = seg0 + cc;
    if (t < BKN) cnt[t] = 0;
    for (int i = t; i < 1024; i += 512) sW[i] = W1[i];
    __syncthreads();
    // phase 1: stage edges in regs (uint4 x1 + scalar x1 = 5/thread);
    // histogram atomic returns the rank
    unsigned pk[5]; int rk[5];
    {
        uint4 q = reinterpret_cast<const uint4*>(packed1 + seg0)[t]; // 16B-aligned
        int i0 = seg0 + 4 * t;
        pk[0] = (i0     < segEnd) ? q.x : 0xFFFFFFFFu;
        pk[1] = (i0 + 1 < segEnd) ? q.y : 0xFFFFFFFFu;
        pk[2] = (i0 + 2 < segEnd) ? q.z : 0xFFFFFFFFu;
        pk[3] = (i0 + 3 < segEnd) ? q.w : 0xFFFFFFFFu;
        int i4 = seg0 + 2048 + t;
        pk[4] = (i4 < segEnd) ? packed1[i4] : 0xFFFFFFFFu;
    }
#pragma unroll
    for (int j = 0; j < 5; ++j)
        if (pk[j] != 0xFFFFFFFFu) rk[j] = atomicAdd(&cnt[pk[j] >> 17], 1);
    __syncthreads();
    // phase 2: 128-wide exclusive scan -> rowPack/start
    int v = (t < BKN) ? cnt[t] : 0;
    if (t < BKN) scn[t] = v;
    __syncthreads();
    for (int off = 1; off < BKN; off <<= 1) {
        int u = (t < BKN && t >= off) ? scn[t - off] : 0;
        __syncthreads();
        if (t < BKN) scn[t] += u;
        __syncthreads();
    }
    int node = b * BKN + t;
    if (t < BKN) {
        int start = seg0 + scn[t] - v;
        stt[t] = start;
        if (node < N_NODES) {
            int vc = (v < 2047) ? v : 2047;
            rowPack[node] = (unsigned)start | ((unsigned)vc << 21);
        }
    }
    __syncthreads();
    // phase 3a: direct scatter (pos = start + rank, provably within segment)
#pragma unroll
    for (int j = 0; j < 5; ++j) {
        if (pk[j] == 0xFFFFFFFFu) continue;
        int pos = stt[pk[j] >> 17] + rk[j];
        srcSorted[pos] = (int)(pk[j] & 0x1FFFFu);
    }
    // phase 3b: p1 = dinv * (x @ W1) for this bucket's 128 nodes (+ sentinel)
    int lane = t & 31;
    for (int r = (t >> 5); r < BKN; r += 16) {
        int nd = b * BKN + r;
        if (nd > N_NODES) break;
        if (nd == N_NODES) {                      // sentinel zero row
            p1[nd * 32 + lane] = __float2half(0.f);
            continue;
        }
        float xv = x[nd * 32 + lane];
        float a = 0.f;
#pragma unroll
        for (int k = 0; k < 32; ++k) {
            float xk = __shfl(xv, k, 32);
            a += xk * sW[k * 32 + lane];
        }
        float di = rsqrtf((float)(cnt[r] + 1));
        p1[nd * 32 + lane] = __float2half(di * a);
    }
}

// ---------------- 4-lane gather (full 64B rows): lane owns ch 8l..8l+7 --------
__device__ __forceinline__ __half2 h2of(const float4& v, int c) {
    return reinterpret_cast<const __half2*>(&v)[c];
}
__device__ __forceinline__ __half2 h2of2(const float2& v, int c) {
    return reinterpret_cast<const __half2*>(&v)[c];
}

__device__ __forceinline__ void gatherRow4(const int* __restrict__ srcSorted,
                                           const float4* __restrict__ P,
                                           int beg, int end, int l,
                                           float* __restrict__ acc /*[8]*/) {
    for (int base = beg; base < end; base += 16) {
        int i0 = base + l,      i1 = base + 4 + l;
        int i2 = base + 8 + l,  i3 = base + 12 + l;
        int sA = (i0 < end) ? srcSorted[i0] : N_NODES;
        int sB = (i1 < end) ? srcSorted[i1] : N_NODES;
        int sC = (i2 < end) ? srcSorted[i2] : N_NODES;
        int sD = (i3 < end) ? srcSorted[i3] : N_NODES;
        float4 v0 = P[__shfl(sA, 0, 4) * 4 + l];
        float4 v1 = P[__shfl(sA, 1, 4) * 4 + l];
        float4 v2 = P[__shfl(sA, 2, 4) * 4 + l];
        float4 v3 = P[__shfl(sA, 3, 4) * 4 + l];
        float4 v4 = P[__shfl(sB, 0, 4) * 4 + l];
        float4 v5 = P[__shfl(sB, 1, 4) * 4 + l];
        float4 v6 = P[__shfl(sB, 2, 4) * 4 + l];
        float4 v7 = P[__shfl(sB, 3, 4) * 4 + l];
        float4 v8 = P[__shfl(sC, 0, 4) * 4 + l];
        float4 v9 = P[__shfl(sC, 1, 4) * 4 + l];
        float4 va = P[__shfl(sC, 2, 4) * 4 + l];
        float4 vb = P[__shfl(sC, 3, 4) * 4 + l];
        float4 vc = P[__shfl(sD, 0, 4) * 4 + l];
        float4 vd = P[__shfl(sD, 1, 4) * 4 + l];
        float4 ve = P[__shfl(sD, 2, 4) * 4 + l];
        float4 vf = P[__shfl(sD, 3, 4) * 4 + l];
#pragma unroll
        for (int c = 0; c < 4; ++c) {
            __half2 s01 = __hadd2(h2of(v0, c), h2of(v1, c));
            __half2 s23 = __hadd2(h2of(v2, c), h2of(v3, c));
            __half2 s45 = __hadd2(h2of(v4, c), h2of(v5, c));
            __half2 s67 = __hadd2(h2of(v6, c), h2of(v7, c));
            __half2 s89 = __hadd2(h2of(v8, c), h2of(v9, c));
            __half2 sab = __hadd2(h2of(va, c), h2of(vb, c));
            __half2 scd = __hadd2(h2of(vc, c), h2of(vd, c));
            __half2 sef = __hadd2(h2of(ve, c), h2of(vf, c));
            __half2 sum = __hadd2(__hadd2(__hadd2(s01, s23), __hadd2(s45, s67)),
                                  __hadd2(__hadd2(s89, sab), __hadd2(scd, sef)));
            float2 f = __half22float2(sum);
            acc[2 * c]     += f.x;
            acc[2 * c + 1] += f.y;
        }
    }
}

// ---------------- 4-lane gather (32B half-table rows): lane owns ch 4l..4l+3 --
__device__ __forceinline__ void gatherRow2(const int* __restrict__ srcSorted,
                                           const float2* __restrict__ P,
                                           int beg, int end, int l,
                                           float* __restrict__ acc /*[4]*/) {
    for (int base = beg; base < end; base += 16) {
        int i0 = base + l,      i1 = base + 4 + l;
        int i2 = base + 8 + l,  i3 = base + 12 + l;
        int sA = (i0 < end) ? srcSorted[i0] : N_NODES;
        int sB = (i1 < end) ? srcSorted[i1] : N_NODES;
        int sC = (i2 < end) ? srcSorted[i2] : N_NODES;
        int sD = (i3 < end) ? srcSorted[i3] : N_NODES;
        float2 v0 = P[__shfl(sA, 0, 4) * 4 + l];
        float2 v1 = P[__shfl(sA, 1, 4) * 4 + l];
        float2 v2 = P[__shfl(sA, 2, 4) * 4 + l];
        float2 v3 = P[__shfl(sA, 3, 4) * 4 + l];
        float2 v4 = P[__shfl(sB, 0, 4) * 4 + l];
        float2 v5 = P[__shfl(sB, 1, 4) * 4 + l];
        float2 v6 = P[__shfl(sB, 2, 4) * 4 + l];
        float2 v7 = P[__shfl(sB, 3, 4) * 4 + l];
        float2 v8 = P[__shfl(sC, 0, 4) * 4 + l];
        float2 v9 = P[__shfl(sC, 1, 4) * 4 + l];
        float2 va = P[__shfl(sC, 2, 4) * 4 + l];
        float2 vb = P[__shfl(sC, 3, 4) * 4 + l];
        float2 vc = P[__shfl(sD, 0, 4) * 4 + l];
        float2 vd = P[__shfl(sD, 1, 4) * 4 + l];
        float2 ve = P[__shfl(sD, 2, 4) * 4 + l];
        float2 vf = P[__shfl(sD, 3, 4) * 4 + l];
#pragma unroll
        for (int c = 0; c < 2; ++c) {
            __half2 s01 = __hadd2(h2of2(v0, c), h2of2(v1, c));
            __half2 s23 = __hadd2(h2of2(v2, c), h2of2(v3, c));
            __half2 s45 = __hadd2(h2of2(v4, c), h2of2(v5, c));
            __half2 s67 = __hadd2(h2of2(v6, c), h2of2(v7, c));
            __half2 s89 = __hadd2(h2of2(v8, c), h2of2(v9, c));
            __half2 sab = __hadd2(h2of2(va, c), h2of2(vb, c));
            __half2 scd = __hadd2(h2of2(vc, c), h2of2(vd, c));
            __half2 sef = __hadd2(h2of2(ve, c), h2of2(vf, c));
            __half2 sum = __hadd2(__hadd2(__hadd2(s01, s23), __hadd2(s45, s67)),
                                  __hadd2(__hadd2(s89, sab), __hadd2(scd, sef)));
            float2 f = __half22float2(sum);
            acc[2 * c]     += f.x;
            acc[2 * c + 1] += f.y;
        }
    }
}

// ---------------- gather layer 1 + relu + layer-2 matmul (4 lanes/node) --------
// Writes the two half-tables p2a (ch 0-15) / p2b (ch 16-31).
__global__ __launch_bounds__(256) void k_gx2(const unsigned* __restrict__ rowPack,
                                             const int* __restrict__ srcSorted,
                                             const __half* __restrict__ p1,
                                             const float* __restrict__ b1,
                                             const float* __restrict__ Wmu,
                                             const float* __restrict__ Wlv,
                                             __half* __restrict__ p2a,
                                             __half* __restrict__ p2b) {
    __shared__ float sW[1024];       // [k][oc], oc: 0-15 mu, 16-31 lv
    __shared__ float sB[32];
    int t = threadIdx.x;
    for (int i = t; i < 1024; i += 256) {
        int k = i >> 5, oc = i & 31;
        sW[i] = (oc < 16) ? Wmu[k * 16 + oc] : Wlv[k * 16 + (oc - 16)];
    }
    if (t < 32) sB[t] = b1[t];
    __syncthreads();
    int l = t & 3;
    int node = blockIdx.x * 64 + (t >> 2);   // 1563*64 covers N + sentinel
    if (node > N_NODES) return;
    const float4* P = (const float4*)p1;
    float4* dstT = (l < 2) ? (float4*)p2a : (float4*)p2b;
    if (node == N_NODES) {                   // sentinel zero rows of p2a/p2b
        dstT[node * 2 + (l & 1)] = make_float4(0.f, 0.f, 0.f, 0.f);
        return;
    }
    unsigned rp = rowPack[node];
    int beg = (int)(rp & 0x1FFFFFu);
    int dg  = (int)(rp >> 21);
    float di = rsqrtf((float)(dg + 1));
    float acc[8] = {0.f, 0.f, 0.f, 0.f, 0.f, 0.f, 0.f, 0.f};
    gatherRow4(srcSorted, P, beg, beg + dg, l, acc);
    float4 ps = P[node * 4 + l];             // self loop analytic
    float h[8];
#pragma unroll
    for (int c = 0; c < 4; ++c) {
        float2 f = __half22float2(h2of(ps, c));
        h[2 * c]     = fmaxf(di * (acc[2 * c]     + f.x) + sB[8 * l + 2 * c],     0.f);
        h[2 * c + 1] = fmaxf(di * (acc[2 * c + 1] + f.y) + sB[8 * l + 2 * c + 1], 0.f);
    }
    float o[8] = {0.f, 0.f, 0.f, 0.f, 0.f, 0.f, 0.f, 0.f};
    const float4* W4 = (const float4*)sW;
#pragma unroll
    for (int m = 0; m < 4; ++m) {
#pragma unroll
        for (int j = 0; j < 8; ++j) {
            float hk = __shfl(h[j], m, 4);   // channel k = 8m+j
            int k = 8 * m + j;
            float4 wa = W4[k * 8 + 2 * l];
            float4 wb = W4[k * 8 + 2 * l + 1];
            o[0] += hk * wa.x; o[1] += hk * wa.y; o[2] += hk * wa.z; o[3] += hk * wa.w;
            o[4] += hk * wb.x; o[5] += hk * wb.y; o[6] += hk * wb.z; o[7] += hk * wb.w;
        }
    }
    __half2 r0 = __floats2half2_rn(di * o[0], di * o[1]);
    __half2 r1 = __floats2half2_rn(di * o[2], di * o[3]);
    __half2 r2 = __floats2half2_rn(di * o[4], di * o[5]);
    __half2 r3 = __floats2half2_rn(di * o[6], di * o[7]);
    float4 st;
    st.x = *reinterpret_cast<float*>(&r0);
    st.y = *reinterpret_cast<float*>(&r1);
    st.z = *reinterpret_cast<float*>(&r2);
    st.w = *reinterpret_cast<float*>(&r3);
    dstT[node * 2 + (l & 1)] = st;
}

// ---------------- gather layer 2, XCD-affine half split -----------------------
// XCDs 0-3 gather the 3.2MB mu table (p2a), XCDs 4-7 the logvar table (p2b);
// each XCD's working set fits its private 4MB L2. 4 lanes/node, float2 loads
// (lane owns ch 4l..4l+3 of its half), 16 edges in flight.
__global__ __launch_bounds__(256) void k_gfin(const unsigned* __restrict__ rowPack,
                                              const int* __restrict__ srcSorted,
                                              const __half* __restrict__ p2a,
                                              const __half* __restrict__ p2b,
                                              const float* __restrict__ bmu,
                                              const float* __restrict__ blv,
                                              float* __restrict__ out) {
    __shared__ float sB[16];
    int t = threadIdx.x;
    int xcd  = blockIdx.x & 7;
    int half = xcd >> 2;
    int nb   = (blockIdx.x >> 3) * 4 + (xcd & 3);
    if (t < 16) sB[t] = half ? blv[t] : bmu[t];
    __syncthreads();
    int l = t & 3;
    int node = nb * 64 + (t >> 2);
    if (node >= N_NODES) return;
    const float2* P = (const float2*)(half ? p2b : p2a);
    unsigned rp = rowPack[node];
    int beg = (int)(rp & 0x1FFFFFu);
    int dg  = (int)(rp >> 21);
    float di = rsqrtf((float)(dg + 1));
    float acc[4] = {0.f, 0.f, 0.f, 0.f};
    gatherRow2(srcSorted, P, beg, beg + dg, l, acc);
    float2 ps = P[node * 4 + l];             // self loop analytic
    float v[4];
#pragma unroll
    for (int c = 0; c < 2; ++c) {
        float2 f = __half22float2(h2of2(ps, c));
        v[2 * c]     = di * (acc[2 * c]     + f.x) + sB[4 * l + 2 * c];
        v[2 * c + 1] = di * (acc[2 * c + 1] + f.y) + sB[4 * l + 2 * c + 1];
    }
    // out: mu rows at [0, N*16), logvar rows at [N*16, 2N*16); lane stores
    // 4 contiguous floats (ch 4l..4l+3) = one float4
    ((float4*)out)[(size_t)half * N_NODES * 4 + (size_t)node * 4 + l] =
        make_float4(v[0], v[1], v[2], v[3]);
}

extern "C" void kernel_launch(void* const* d_in, const int* in_sizes, int n_in,
                              void* d_out, int out_size, void* d_ws, size_t ws_size,
                              hipStream_t stream) {
    const float* x   = (const float*)d_in[0];
    const int*   ei  = (const int*)d_in[1];
    const float* W1  = (const float*)d_in[2];
    const float* b1  = (const float*)d_in[3];
    const float* Wmu = (const float*)d_in[4];
    const float* bmu = (const float*)d_in[5];
    const float* Wlv = (const float*)d_in[6];
    const float* blv = (const float*)d_in[7];
    float* out = (float*)d_out;

    const int* src = ei;            // edge_index[0]
    const int* dst = ei + N_EDGES;  // edge_index[1]

    // workspace (4B units), 256B-aligned big buffers for float4 access:
    //  cursor1[782] (COUNTS, zeroed by memset below)
    //  | rowPack[N] | pad
    //  | packed1[782*2560] | srcSorted[782*2560]
    //  | p1[(N+1)*32 halves] | p2a[(N+1)*16 halves] | p2b[(N+1)*16 halves]
    size_t off = 0;
    int* cursor1 = (int*)d_ws;                          off += NCB;
    unsigned* rowPack = (unsigned*)((int*)d_ws + off);  off += N_NODES;
    off = (off + 63) & ~(size_t)63;                     // 256B align
    unsigned* packed1 = (unsigned*)((int*)d_ws + off);  off += (size_t)NCB * CAPC;
    off = (off + 63) & ~(size_t)63;
    int* srcSorted    = (int*)d_ws + off;               off += (size_t)NCB * CAPC;
    off = (off + 63) & ~(size_t)63;
    __half* p1h = (__half*)((int*)d_ws + off);          off += (size_t)(N_NODES + 1) * 16;
    off = (off + 63) & ~(size_t)63;
    __half* p2a = (__half*)((int*)d_ws + off);          off += (size_t)(N_NODES + 1) * 8;
    off = (off + 63) & ~(size_t)63;
    __half* p2b = (__half*)((int*)d_ws + off);

    // cursor init: counts-relative cursors -> plain zeroing (capture-legal)
    hipMemsetAsync(d_ws, 0, (size_t)NCB * sizeof(int), stream);
    k_part1<<<P1_BLOCKS, 1024, 0, stream>>>(src, dst, cursor1, packed1);
    k_csrx <<<NCB, 512, 0, stream>>>(packed1, cursor1, x, W1,
                                     rowPack, srcSorted, p1h);
    k_gx2  <<<NBF_G, 256, 0, stream>>>(rowPack, srcSorted, p1h,
                                       b1, Wmu, Wlv, p2a, p2b);
    k_gfin <<<NFIN_B, 256, 0, stream>>>(rowPack, srcSorted, p2a, p2b,
                                        bmu, blv, out);
}

// Round 10
// 178.799 us; speedup vs baseline: 1.0422x; 1.0422x over previous
//
#include <hip/hip_runtime.h>
#include <hip/hip_fp16.h>

#define N_NODES 100000
#define N_EDGES 1600000
// single-level partition: 128-node buckets, bucket = dst >> 7
#define NCB 782             // ceil(N/128)
#define CAPC 2560           // mean 2046, sigma ~45 -> +11 sigma, 64B-aligned
#define P1_BLOCKS 391       // ceil((E/4)/1024) int4-threads
#define BKN 128             // nodes per CSR bucket
#define NBF_G 1563          // gather grid: 64 nodes/block, covers N + sentinel

// cursor1[] is COUNTS (0-initialized via hipMemsetAsync); absolute position =
// bucket*CAPC + relative offset.
// rowPack[n] = rowBeg | (deg << 21): beg < 782*2560 = 2.0M < 2^21; deg capped
// at 2047. dinv recomputed as rsqrtf(deg+1) by consumers.

// ---------------- pass 1: partition edges into 782 buckets ----------------
__global__ __launch_bounds__(1024) void k_part1(const int* __restrict__ src,
                                                const int* __restrict__ dst,
                                                int* __restrict__ cursor1,
                                                unsigned* __restrict__ packed1) {
    __shared__ int bh[NCB];
    __shared__ int base[NCB];
    int t = threadIdx.x;
    for (int i = t; i < NCB; i += 1024) bh[i] = 0;
    __syncthreads();
    int g = blockIdx.x * 1024 + t;       // int4-group index; 4 edges/thread
    int d[4], s[4], r[4];
    if (g < N_EDGES / 4) {
        int4 d4 = reinterpret_cast<const int4*>(dst)[g];
        int4 s4 = reinterpret_cast<const int4*>(src)[g];
        d[0] = d4.x; d[1] = d4.y; d[2] = d4.z; d[3] = d4.w;
        s[0] = s4.x; s[1] = s4.y; s[2] = s4.z; s[3] = s4.w;
    } else {
        d[0] = d[1] = d[2] = d[3] = -1;
    }
#pragma unroll
    for (int j = 0; j < 4; ++j)
        if (d[j] >= 0) r[j] = atomicAdd(&bh[((unsigned)d[j]) >> 7], 1);
    __syncthreads();
    for (int i = t; i < NCB; i += 1024) {
        int c = bh[i];
        base[i] = i * CAPC + ((c > 0) ? atomicAdd(&cursor1[i], c) : 0);
    }
    __syncthreads();
#pragma unroll
    for (int j = 0; j < 4; ++j) {
        if (d[j] < 0) continue;
        unsigned dd = (unsigned)d[j];
        int b = dd >> 7;
        int pos = base[b] + r[j];
        if (pos < (b + 1) * CAPC)   // statistically impossible overflow guard
            packed1[pos] = ((dd & 127u) << 17) | (unsigned)s[j];
    }
}

// ---------------- fused: per-bucket CSR build + rowPack + p1 = dinv*(x@W1) ----
// Barrier-diet version: 4 barriers total (was 17). Two-wave shfl scan replaces
// the 14-barrier ladder; x rows for the phase-3b matmul are PREFETCHED into
// registers at kernel entry so the tail matmul consumes landed data.
__global__ __launch_bounds__(512) void k_csrx(const unsigned* __restrict__ packed1,
                                              const int* __restrict__ cursor1,
                                              const float* __restrict__ x,
                                              const float* __restrict__ W1,
                                              unsigned* __restrict__ rowPack,
                                              int* __restrict__ srcSorted,
                                              __half* __restrict__ p1) {
    __shared__ int cnt[BKN];
    __shared__ int stt[BKN];
    __shared__ int wtot;
    __shared__ float sW[1024];
    int t = threadIdx.x;
    int b = blockIdx.x;
    int seg0 = b * CAPC;
    int cc = cursor1[b]; if (cc > CAPC) cc = CAPC;
    int segEnd = seg0 + cc;
    if (t < BKN) cnt[t] = 0;
    for (int i = t; i < 1024; i += 512) sW[i] = W1[i];
    // stage edges in regs (uint4 x1 + scalar x1 = 5/thread)
    unsigned pk[5]; int rk[5];
    {
        uint4 q = reinterpret_cast<const uint4*>(packed1 + seg0)[t]; // 16B-aligned
        int i0 = seg0 + 4 * t;
        pk[0] = (i0     < segEnd) ? q.x : 0xFFFFFFFFu;
        pk[1] = (i0 + 1 < segEnd) ? q.y : 0xFFFFFFFFu;
        pk[2] = (i0 + 2 < segEnd) ? q.z : 0xFFFFFFFFu;
        pk[3] = (i0 + 3 < segEnd) ? q.w : 0xFFFFFFFFu;
        int i4 = seg0 + 2048 + t;
        pk[4] = (i4 < segEnd) ? packed1[i4] : 0xFFFFFFFFu;
    }
    // prefetch the 8 x-rows this thread will need in phase 3b
    float xv[8];
    int lane = t & 31;
    int rbase = t >> 5;   // 0..15
#pragma unroll
    for (int q = 0; q < 8; ++q) {
        int nd = b * BKN + rbase + q * 16;
        xv[q] = (nd < N_NODES) ? x[nd * 32 + lane] : 0.f;
    }
    __syncthreads();                                   // (1) cnt init visible
    // phase 1: histogram; the LDS atomic returns the rank
#pragma unroll
    for (int j = 0; j < 5; ++j)
        if (pk[j] != 0xFFFFFFFFu) rk[j] = atomicAdd(&cnt[pk[j] >> 17], 1);
    __syncthreads();                                   // (2) histogram done
    // phase 2: two-wave shfl scan (wave0: nodes 0-63, wave1: 64-127)
    int v = 0, run = 0;
    if (t < BKN) {
        v = cnt[t];
        run = v;
#pragma unroll
        for (int off = 1; off < 64; off <<= 1) {
            int u = __shfl_up(run, off, 64);
            if ((t & 63) >= off) run += u;
        }
        if (t == 63) wtot = run;
    }
    __syncthreads();                                   // (3) wave0 total visible
    if (t < BKN) {
        if (t >= 64) run += wtot;
        int start = seg0 + run - v;
        stt[t] = start;
        int node = b * BKN + t;
        if (node < N_NODES) {
            int vc = (v < 2047) ? v : 2047;
            rowPack[node] = (unsigned)start | ((unsigned)vc << 21);
        }
    }
    __syncthreads();                                   // (4) stt visible
    // phase 3a: direct scatter (pos = start + rank, provably within segment)
#pragma unroll
    for (int j = 0; j < 5; ++j) {
        if (pk[j] == 0xFFFFFFFFu) continue;
        int pos = stt[pk[j] >> 17] + rk[j];
        srcSorted[pos] = (int)(pk[j] & 0x1FFFFu);
    }
    // phase 3b: p1 = dinv * (x @ W1) from prefetched xv (+ sentinel row)
#pragma unroll
    for (int q = 0; q < 8; ++q) {
        int r = rbase + q * 16;
        int nd = b * BKN + r;
        if (nd > N_NODES) break;
        if (nd == N_NODES) {                      // sentinel zero row
            p1[nd * 32 + lane] = __float2half(0.f);
            continue;
        }
        float a = 0.f;
#pragma unroll
        for (int k = 0; k < 32; ++k) {
            float xk = __shfl(xv[q], k, 32);
            a += xk * sW[k * 32 + lane];
        }
        float di = rsqrtf((float)(cnt[r] + 1));
        p1[nd * 32 + lane] = __float2half(di * a);
    }
}

// ---------------- 4-lane gather: lane owns channels 8l..8l+7, 16B loads --------
// 16 edges in flight per iteration (16 independent float4 loads issued before
// any consumption) to hide L2/L3 gather latency. Tail edges load the sentinel
// zero row (index N_NODES) instead of branching. fp16 8-term tree partials ->
// fp32 flush.
__device__ __forceinline__ __half2 h2of(const float4& v, int c) {
    return reinterpret_cast<const __half2*>(&v)[c];
}

__device__ __forceinline__ void gatherRow4(const int* __restrict__ srcSorted,
                                           const float4* __restrict__ P,
                                           int beg, int end, int l,
                                           float* __restrict__ acc /*[8]*/) {
    for (int base = beg; base < end; base += 16) {
        int i0 = base + l,      i1 = base + 4 + l;
        int i2 = base + 8 + l,  i3 = base + 12 + l;
        int sA = (i0 < end) ? srcSorted[i0] : N_NODES;
        int sB = (i1 < end) ? srcSorted[i1] : N_NODES;
        int sC = (i2 < end) ? srcSorted[i2] : N_NODES;
        int sD = (i3 < end) ? srcSorted[i3] : N_NODES;
        float4 v0 = P[__shfl(sA, 0, 4) * 4 + l];
        float4 v1 = P[__shfl(sA, 1, 4) * 4 + l];
        float4 v2 = P[__shfl(sA, 2, 4) * 4 + l];
        float4 v3 = P[__shfl(sA, 3, 4) * 4 + l];
        float4 v4 = P[__shfl(sB, 0, 4) * 4 + l];
        float4 v5 = P[__shfl(sB, 1, 4) * 4 + l];
        float4 v6 = P[__shfl(sB, 2, 4) * 4 + l];
        float4 v7 = P[__shfl(sB, 3, 4) * 4 + l];
        float4 v8 = P[__shfl(sC, 0, 4) * 4 + l];
        float4 v9 = P[__shfl(sC, 1, 4) * 4 + l];
        float4 va = P[__shfl(sC, 2, 4) * 4 + l];
        float4 vb = P[__shfl(sC, 3, 4) * 4 + l];
        float4 vc = P[__shfl(sD, 0, 4) * 4 + l];
        float4 vd = P[__shfl(sD, 1, 4) * 4 + l];
        float4 ve = P[__shfl(sD, 2, 4) * 4 + l];
        float4 vf = P[__shfl(sD, 3, 4) * 4 + l];
#pragma unroll
        for (int c = 0; c < 4; ++c) {
            __half2 s01 = __hadd2(h2of(v0, c), h2of(v1, c));
            __half2 s23 = __hadd2(h2of(v2, c), h2of(v3, c));
            __half2 s45 = __hadd2(h2of(v4, c), h2of(v5, c));
            __half2 s67 = __hadd2(h2of(v6, c), h2of(v7, c));
            __half2 s89 = __hadd2(h2of(v8, c), h2of(v9, c));
            __half2 sab = __hadd2(h2of(va, c), h2of(vb, c));
            __half2 scd = __hadd2(h2of(vc, c), h2of(vd, c));
            __half2 sef = __hadd2(h2of(ve, c), h2of(vf, c));
            __half2 sum = __hadd2(__hadd2(__hadd2(s01, s23), __hadd2(s45, s67)),
                                  __hadd2(__hadd2(s89, sab), __hadd2(scd, sef)));
            float2 f = __half22float2(sum);
            acc[2 * c]     += f.x;
            acc[2 * c + 1] += f.y;
        }
    }
}

// ---------------- gather layer 1 + relu + layer-2 matmul (4 lanes/node) --------
__global__ __launch_bounds__(256) void k_gx2(const unsigned* __restrict__ rowPack,
                                             const int* __restrict__ srcSorted,
                                             const __half* __restrict__ p1,
                                             const float* __restrict__ b1,
                                             const float* __restrict__ Wmu,
                                             const float* __restrict__ Wlv,
                                             __half* __restrict__ p2) {
    __shared__ float sW[1024];       // [k][oc], oc: 0-15 mu, 16-31 lv
    __shared__ float sB[32];
    int t = threadIdx.x;
    for (int i = t; i < 1024; i += 256) {
        int k = i >> 5, oc = i & 31;
        sW[i] = (oc < 16) ? Wmu[k * 16 + oc] : Wlv[k * 16 + (oc - 16)];
    }
    if (t < 32) sB[t] = b1[t];
    __syncthreads();
    int l = t & 3;
    int node = blockIdx.x * 64 + (t >> 2);   // 1563*64 covers N + sentinel
    if (node > N_NODES) return;
    const float4* P = (const float4*)p1;
    if (node == N_NODES) {                   // sentinel zero row of p2
        ((float4*)p2)[node * 4 + l] = make_float4(0.f, 0.f, 0.f, 0.f);
        return;
    }
    unsigned rp = rowPack[node];
    int beg = (int)(rp & 0x1FFFFFu);
    int dg  = (int)(rp >> 21);
    float di = rsqrtf((float)(dg + 1));
    float acc[8] = {0.f, 0.f, 0.f, 0.f, 0.f, 0.f, 0.f, 0.f};
    gatherRow4(srcSorted, P, beg, beg + dg, l, acc);
    float4 ps = P[node * 4 + l];             // self loop analytic
    float h[8];
#pragma unroll
    for (int c = 0; c < 4; ++c) {
        float2 f = __half22float2(h2of(ps, c));
        h[2 * c]     = fmaxf(di * (acc[2 * c]     + f.x) + sB[8 * l + 2 * c],     0.f);
        h[2 * c + 1] = fmaxf(di * (acc[2 * c + 1] + f.y) + sB[8 * l + 2 * c + 1], 0.f);
    }
    float o[8] = {0.f, 0.f, 0.f, 0.f, 0.f, 0.f, 0.f, 0.f};
    const float4* W4 = (const float4*)sW;
#pragma unroll
    for (int m = 0; m < 4; ++m) {
#pragma unroll
        for (int j = 0; j < 8; ++j) {
            float hk = __shfl(h[j], m, 4);   // channel k = 8m+j
            int k = 8 * m + j;
            float4 wa = W4[k * 8 + 2 * l];
            float4 wb = W4[k * 8 + 2 * l + 1];
            o[0] += hk * wa.x; o[1] += hk * wa.y; o[2] += hk * wa.z; o[3] += hk * wa.w;
            o[4] += hk * wb.x; o[5] += hk * wb.y; o[6] += hk * wb.z; o[7] += hk * wb.w;
        }
    }
    __half2 r0 = __floats2half2_rn(di * o[0], di * o[1]);
    __half2 r1 = __floats2half2_rn(di * o[2], di * o[3]);
    __half2 r2 = __floats2half2_rn(di * o[4], di * o[5]);
    __half2 r3 = __floats2half2_rn(di * o[6], di * o[7]);
    float4 st;
    st.x = *reinterpret_cast<float*>(&r0);
    st.y = *reinterpret_cast<float*>(&r1);
    st.z = *reinterpret_cast<float*>(&r2);
    st.w = *reinterpret_cast<float*>(&r3);
    ((float4*)p2)[node * 4 + l] = st;
}

// ---------------- gather layer 2 + mu/logvar epilogue (4 lanes/node) ----------
__global__ __launch_bounds__(256) void k_gfin(const unsigned* __restrict__ rowPack,
                                              const int* __restrict__ srcSorted,
                                              const __half* __restrict__ p2,
                                              const float* __restrict__ bmu,
                                              const float* __restrict__ blv,
                                              float* __restrict__ out) {
    __shared__ float sB[32];
    int t = threadIdx.x;
    if (t < 32) sB[t] = (t < 16) ? bmu[t] : blv[t - 16];
    __syncthreads();
    int l = t & 3;
    int node = blockIdx.x * 64 + (t >> 2);
    if (node >= N_NODES) return;
    const float4* P = (const float4*)p2;
    unsigned rp = rowPack[node];
    int beg = (int)(rp & 0x1FFFFFu);
    int dg  = (int)(rp >> 21);
    float di = rsqrtf((float)(dg + 1));
    float acc[8] = {0.f, 0.f, 0.f, 0.f, 0.f, 0.f, 0.f, 0.f};
    gatherRow4(srcSorted, P, beg, beg + dg, l, acc);
    float4 ps = P[node * 4 + l];
    float v[8];
#pragma unroll
    for (int c = 0; c < 4; ++c) {
        float2 f = __half22float2(h2of(ps, c));
        v[2 * c]     = di * (acc[2 * c]     + f.x) + sB[8 * l + 2 * c];
        v[2 * c + 1] = di * (acc[2 * c + 1] + f.y) + sB[8 * l + 2 * c + 1];
    }
    float4 o0 = make_float4(v[0], v[1], v[2], v[3]);
    float4 o1 = make_float4(v[4], v[5], v[6], v[7]);
    float4* dst4 = (l < 2) ? (float4*)out
                           : (float4*)(out + (size_t)N_NODES * 16);
    int b4 = node * 4 + (l & 1) * 2;
    dst4[b4]     = o0;
    dst4[b4 + 1] = o1;
}

extern "C" void kernel_launch(void* const* d_in, const int* in_sizes, int n_in,
                              void* d_out, int out_size, void* d_ws, size_t ws_size,
                              hipStream_t stream) {
    const float* x   = (const float*)d_in[0];
    const int*   ei  = (const int*)d_in[1];
    const float* W1  = (const float*)d_in[2];
    const float* b1  = (const float*)d_in[3];
    const float* Wmu = (const float*)d_in[4];
    const float* bmu = (const float*)d_in[5];
    const float* Wlv = (const float*)d_in[6];
    const float* blv = (const float*)d_in[7];
    float* out = (float*)d_out;

    const int* src = ei;            // edge_index[0]
    const int* dst = ei + N_EDGES;  // edge_index[1]

    // workspace (4B units), 256B-aligned big buffers for float4 access:
    //  cursor1[782] (COUNTS, zeroed by memset below)
    //  | rowPack[N] | pad
    //  | packed1[782*2560] | srcSorted[782*2560]
    //  | p1[(N+1)*32 halves] | p2[(N+1)*32 halves]
    size_t off = 0;
    int* cursor1 = (int*)d_ws;                          off += NCB;
    unsigned* rowPack = (unsigned*)((int*)d_ws + off);  off += N_NODES;
    off = (off + 63) & ~(size_t)63;                     // 256B align
    unsigned* packed1 = (unsigned*)((int*)d_ws + off);  off += (size_t)NCB * CAPC;
    off = (off + 63) & ~(size_t)63;
    int* srcSorted    = (int*)d_ws + off;               off += (size_t)NCB * CAPC;
    off = (off + 63) & ~(size_t)63;
    __half* p1h = (__half*)((int*)d_ws + off);          off += (size_t)(N_NODES + 1) * 16;
    off = (off + 63) & ~(size_t)63;
    __half* p2h = (__half*)((int*)d_ws + off);

    // cursor init: counts-relative cursors -> plain zeroing (capture-legal)
    hipMemsetAsync(d_ws, 0, (size_t)NCB * sizeof(int), stream);
    k_part1<<<P1_BLOCKS, 1024, 0, stream>>>(src, dst, cursor1, packed1);
    k_csrx <<<NCB, 512, 0, stream>>>(packed1, cursor1, x, W1,
                                     rowPack, srcSorted, p1h);
    k_gx2  <<<NBF_G, 256, 0, stream>>>(rowPack, srcSorted, p1h,
                                       b1, Wmu, Wlv, p2h);
    k_gfin <<<NBF_G, 256, 0, stream>>>(rowPack, srcSorted, p2h,
                                       bmu, blv, out);
}